// Round 11
// baseline (158.755 us; speedup 1.0000x reference)
//
#include <hip/hip_runtime.h>

#define N     4096
#define FIN   256
#define CC    256   // HEADS * F_OUT
#define HEADS 4
#define FOUT  64
#define XPITCH 266  // FIN+10 shorts = 133 dwords (odd) -> conflict-free

typedef __attribute__((ext_vector_type(8))) short bf16x8;
typedef __attribute__((ext_vector_type(4))) float f32x4;
typedef __attribute__((ext_vector_type(2))) float f32x2;

// packed f32->bf16 (RNE), one instr for two values
__device__ inline unsigned cvtpk(float lo, float hi) {
    unsigned r;
    asm("v_cvt_pk_bf16_f32 %0, %1, %2" : "=v"(r) : "v"(lo), "v"(hi));
    return r;
}
// dual-FP32 packed multiply (CDNA full-rate)
__device__ inline f32x2 pkmul(f32x2 a, f32x2 b) {
    f32x2 r;
    asm("v_pk_mul_f32 %0, %1, %2" : "=v"(r) : "v"(a), "v"(b));
    return r;
}
// two masked edge weights -> one packed bf16 dword (probe-validated: this
// form is VALU-floor ~4.5 instr/edge; k2b is VALU-issue-bound per r8 PMC).
__device__ inline unsigned wpair(f32x2 E1p, float4 dd, unsigned bits, int jj) {
    const f32x2 plo = pkmul(E1p, (f32x2){dd.x, dd.y});
    const f32x2 phi = pkmul(E1p, (f32x2){dd.z, dd.w});
    const unsigned mlo = (unsigned)(((int)(bits << (31 - jj))) >> 31);
    const unsigned mhi = (unsigned)(((int)(bits << (30 - jj))) >> 31);
    const float lo = __builtin_bit_cast(float,
        __builtin_bit_cast(unsigned, fmaxf(plo[0], plo[1])) & mlo);
    const float hi = __builtin_bit_cast(float,
        __builtin_bit_cast(unsigned, fmaxf(phi[0], phi[1])) & mhi);
    return cvtpk(lo, hi);
}

// ---------------------------------------------------------------------------
// k1a: h = x@W via MFMA (one head x 64 n-rows per block, grid 256) -> hF in
// fragment order; e1/e2 stored PRE-EXPONENTIATED as {exp(e), exp(0.2e)}.
// ---------------------------------------------------------------------------
__global__ __launch_bounds__(512) void gat_k1a(const float* __restrict__ x,
                                               const float* __restrict__ W,
                                               const float* __restrict__ a,
                                               short* __restrict__ hF,
                                               float2* __restrict__ e1f,
                                               float2* __restrict__ e2f) {
    __shared__ __align__(16) short xs[64][XPITCH];    // 34.0 KB
    __shared__ __align__(16) short wts[64][XPITCH];   // 34.0 KB
    __shared__ __align__(16) short hbuf[64][74];      //  9.5 KB
    const int t    = threadIdx.x;
    const int bid  = blockIdx.x;
    const int lane = t & 63;
    const int w    = t >> 6;          // 0..7

    const int hd = bid >> 6;
    const int n0 = (bid & 63) * 64;
    const int c0 = hd * 64;
    const int m = lane & 15;
    const int q = lane >> 4;

    {   // stage x rows n0..n0+63 as bf16 (4096 float4 over 512 threads)
        const float4* xsrc = (const float4*)(x + (size_t)n0 * FIN);
        #pragma unroll
        for (int it = 0; it < 8; ++it) {
            const int fi = it * 512 + t;
            const float4 v = xsrc[fi];
            uint2 o;
            o.x = cvtpk(v.x, v.y);
            o.y = cvtpk(v.z, v.w);
            *(uint2*)&xs[fi >> 6][(fi & 63) * 4] = o;
        }
    }
    {   // stage W^T column slice (coalesced across c)
        const int c  = t & 63;
        const int k4 = (t >> 6) * 4;  // 0..28 step 4
        #pragma unroll
        for (int it = 0; it < 8; ++it) {
            const int k = it * 32 + k4;
            const float w0 = W[(k + 0) * CC + c0 + c];
            const float w1 = W[(k + 1) * CC + c0 + c];
            const float w2 = W[(k + 2) * CC + c0 + c];
            const float w3 = W[(k + 3) * CC + c0 + c];
            uint2 o;
            o.x = cvtpk(w0, w1);
            o.y = cvtpk(w2, w3);
            *(uint2*)&wts[c][k] = o;
        }
    }
    __syncthreads();

    if (w < 4) {   // compute waves: w = row-group
        f32x4 acc[4];
        #pragma unroll
        for (int ct = 0; ct < 4; ++ct) acc[ct] = (f32x4){0.f, 0.f, 0.f, 0.f};

        #pragma unroll
        for (int ks = 0; ks < 8; ++ks) {
            const bf16x8 af = *(const bf16x8*)&xs[w * 16 + m][ks * 32 + q * 8];
            #pragma unroll
            for (int ct = 0; ct < 4; ++ct) {
                const bf16x8 bf_ = *(const bf16x8*)&wts[ct * 16 + m][ks * 32 + q * 8];
                acc[ct] = __builtin_amdgcn_mfma_f32_16x16x32_bf16(af, bf_, acc[ct], 0, 0, 0);
            }
        }

        // e1/e2 from fp32 acc (C layout: row=q*4+r, col=ct*16+m)
        const float a1v[4] = {a[m], a[16 + m], a[32 + m], a[48 + m]};
        const float a2v[4] = {a[64 + m], a[80 + m], a[96 + m], a[112 + m]};
        #pragma unroll
        for (int r = 0; r < 4; ++r) {
            float s1 = 0.f, s2 = 0.f;
            #pragma unroll
            for (int ct = 0; ct < 4; ++ct) {
                s1 = fmaf(acc[ct][r], a1v[ct], s1);
                s2 = fmaf(acc[ct][r], a2v[ct], s2);
            }
            #pragma unroll
            for (int sh = 1; sh < 16; sh <<= 1) {
                s1 += __shfl_xor(s1, sh, 64);
                s2 += __shfl_xor(s2, sh, 64);
            }
            if (m == 0) {
                const int n = n0 + w * 16 + q * 4 + r;
                e1f[(size_t)hd * N + n] = make_float2(__expf(s1), __expf(0.2f * s1));
                e2f[(size_t)hd * N + n] = make_float2(__expf(s2), __expf(0.2f * s2));
            }
        }

        // transpose h tile to hbuf[c][n-local]: packed dword stores
        #pragma unroll
        for (int ct = 0; ct < 4; ++ct) {
            const unsigned lo = cvtpk(acc[ct][0], acc[ct][1]);
            const unsigned hi = cvtpk(acc[ct][2], acc[ct][3]);
            unsigned* hp = (unsigned*)&hbuf[ct * 16 + m][w * 16 + q * 4];
            hp[0] = lo;
            hp[1] = hi;
        }
    }
    __syncthreads();

    // write hF in fragment order: frag(jc32, ft) lane lp holds
    // h[f=ft*16+(lp&15)][j = jc32*32 + (lp>>4)*8 + 0..7]
    {
        const int lp = t & 63;
        const int ft = (t >> 6) & 3;
        const int c2 = t >> 8;
        const int mm = lp & 15;
        const int qq = lp >> 4;
        const bf16x8 hv = *(const bf16x8*)&hbuf[ft * 16 + mm][c2 * 32 + qq * 8];
        const size_t jc = (size_t)(n0 >> 5) + c2;
        *(bf16x8*)(hF + ((((size_t)hd * 128 + jc) * 4 + ft) * 64 + lp) * 8) = hv;
    }
}

// ---------------------------------------------------------------------------
// k1b: adj -> bitmask. Zero LDS, grid 2048 x 256 (HBM floor for the 64 MB
// stream, ~10-11 us). Wave = half-row, 8 batched int4 loads, shfl_xor pack.
// ---------------------------------------------------------------------------
__global__ __launch_bounds__(256) void gat_k1b(const int* __restrict__ adj,
                                               unsigned* __restrict__ adjb) {
    const int t    = threadIdx.x;
    const int lane = t & 63;
    const int w    = t >> 6;
    const int row  = blockIdx.x * 2 + (w >> 1);
    const int half = w & 1;
    const int4* arow4 = (const int4*)(adj + (size_t)row * N) + half * 512;
    unsigned*   drow  = adjb + (size_t)row * 128 + half * 64;

    int4 ca[8];
    #pragma unroll
    for (int k = 0; k < 8; ++k)
        ca[k] = arow4[k * 64 + lane];          // batched: 8 KB in flight
    #pragma unroll
    for (int k = 0; k < 8; ++k) {
        const int4 v = ca[k];
        unsigned n = (v.x != 0 ? 1u : 0u) | (v.y != 0 ? 2u : 0u) |
                     (v.z != 0 ? 4u : 0u) | (v.w != 0 ? 8u : 0u);
        unsigned b  = n   | ((unsigned)__shfl_xor((int)n,   1, 64) << 4);
        unsigned hw = b   | ((unsigned)__shfl_xor((int)b,   2, 64) << 8);
        unsigned d  = hw  | ((unsigned)__shfl_xor((int)hw,  4, 64) << 16);
        if ((lane & 7) == 0) drow[k * 8 + (lane >> 3)] = d;
    }
}

// ---------------------------------------------------------------------------
// k2b: numerator + Z partials via MFMA. IDENTICAL body to round 9; ONE
// change: __launch_bounds__(512, 8) -- R9 omitted the min-waves arg, the
// allocator exceeded 64 VGPR, and the 4-blocks/CU geometry silently ran at
// 2 blocks/CU (R9 total matched that model exactly). With VGPR<=64 (R8
// measured the natural requirement = 64): 4 blocks x 8 waves = 32 waves/CU,
// LDS 4x30KB=120KB, nothing caps. Sibling blocks fill the 40% barrier idle.
// ---------------------------------------------------------------------------
__global__ __launch_bounds__(512, 8) void gat_k2b(const short* __restrict__ hF,
                                                  const unsigned* __restrict__ adjb,
                                                  const float2* __restrict__ e1f,
                                                  const float2* __restrict__ e2f,
                                                  float* __restrict__ num,
                                                  float* __restrict__ Zp) {
    __shared__ __align__(16) short    hstage[2][4096];  // 2 x 8 KB
    __shared__ __align__(16) float    e2s[1024];        // 4 KB (512 pairs)
    __shared__ __align__(16) unsigned adjl[128 * 20];   // 10 KB, pitch 20 dw
    const int t    = threadIdx.x;
    const int lane = t & 63;
    const int g    = t >> 6;
    const int bid  = blockIdx.x;
    const int xcd  = bid & 7;
    const int idx  = bid >> 3;                  // 0..127
    const int hd   = idx & 3;
    const int jc   = (idx >> 2) & 7;            // 8 chunks of 512 j
    const int it   = xcd | ((idx >> 5) << 3);   // XCD-affine i-tile (32 vals)
    const int i0   = it * 128;
    const int j0   = jc * 512;
    const int m    = lane & 15;
    const int q    = lane >> 4;
    const int slice = hd * 8 + jc;

    // stage e2 slice (512 pairs = 256 float4)
    if (t < 256)
        ((float4*)e2s)[t] = ((const float4*)(e2f + (size_t)hd * N + j0))[t];
    // stage adj slice: 128 rows x 16 dwords (this jc), pitch 20 dw (80 B;
    // byte-read banks: m*20 mod 32 -> 2-way on rows, free)
    {
        const int row  = t >> 2;                // 0..127
        const int part = t & 3;                 // uint4 0..3
        const uint4* src = (const uint4*)(adjb + (size_t)(i0 + row) * 128 + jc * 16);
        uint4* dst = (uint4*)(adjl + row * 20);
        dst[part] = src[part];
    }
    // prologue: stage macro 0 of hF (8 KB = 512 x uint4)
    const uint4* gsrc = (const uint4*)(hF + ((size_t)hd * 128 + jc * 16) * 2048);
    ((uint4*)hstage[0])[t] = gsrc[t];
    __syncthreads();

    const int    rowi = i0 + g * 16 + m;
    const float2 E1r  = e1f[(size_t)hd * N + rowi];
    const f32x2  E1pk = (f32x2){E1r.x, E1r.y};

    bf16x8 onesb;
    #pragma unroll
    for (int e = 0; e < 8; ++e) onesb[e] = (short)0x3F80;   // bf16(1.0)

    f32x4 acc[4];
    #pragma unroll
    for (int ft = 0; ft < 4; ++ft) acc[ft] = (f32x4){0.f, 0.f, 0.f, 0.f};
    f32x4 accz = (f32x4){0.f, 0.f, 0.f, 0.f};

    const unsigned char* ab = ((const unsigned char*)adjl) + (g * 16 + m) * 80 + q;

    int cur = 0;
    for (int mac = 0; mac < 8; ++mac) {
        // issue next macro's global loads FIRST (latency hides under compute)
        const uint4 v = gsrc[(size_t)((mac + 1) & 7) * 512 + t];

        const short* hb = &hstage[cur][0];
        #pragma unroll
        for (int s = 0; s < 2; ++s) {
            const int jloc = mac * 64 + s * 32 + q * 8;
            const bf16x8 b0 = *(const bf16x8*)(hb + s * 2048 + 0 * 512 + lane * 8);
            const bf16x8 b1 = *(const bf16x8*)(hb + s * 2048 + 1 * 512 + lane * 8);
            const bf16x8 b2 = *(const bf16x8*)(hb + s * 2048 + 2 * 512 + lane * 8);
            const bf16x8 b3 = *(const bf16x8*)(hb + s * 2048 + 3 * 512 + lane * 8);
            const float4* ev = (const float4*)&e2s[2 * jloc];
            const float4 d0 = ev[0], d1 = ev[1], d2 = ev[2], d3 = ev[3];
            const unsigned bits = (unsigned)ab[(mac * 2 + s) * 4];

            uint4 au;
            au.x = wpair(E1pk, d0, bits, 0);
            au.y = wpair(E1pk, d1, bits, 2);
            au.z = wpair(E1pk, d2, bits, 4);
            au.w = wpair(E1pk, d3, bits, 6);
            const bf16x8 af = __builtin_bit_cast(bf16x8, au);

            acc[0] = __builtin_amdgcn_mfma_f32_16x16x32_bf16(af, b0, acc[0], 0, 0, 0);
            acc[1] = __builtin_amdgcn_mfma_f32_16x16x32_bf16(af, b1, acc[1], 0, 0, 0);
            acc[2] = __builtin_amdgcn_mfma_f32_16x16x32_bf16(af, b2, acc[2], 0, 0, 0);
            acc[3] = __builtin_amdgcn_mfma_f32_16x16x32_bf16(af, b3, acc[3], 0, 0, 0);
            accz   = __builtin_amdgcn_mfma_f32_16x16x32_bf16(af, onesb, accz, 0, 0, 0);
        }

        if (mac < 7) {
            ((uint4*)hstage[cur ^ 1])[t] = v;   // write-late (stalls only on vmcnt)
            __syncthreads();
            cur ^= 1;
        }
    }

    // Z partials: accz reg r = masked-quantized weight row-sum (cols equal)
    if (m == 0) {
        #pragma unroll
        for (int r = 0; r < 4; ++r)
            Zp[(size_t)slice * N + i0 + g * 16 + q * 4 + r] = accz[r];
    }

    // numerator partial: C layout row=q*4+r, col=ft*16+m; plain stores
    {
        float* nrow = num + ((size_t)slice * N + i0 + g * 16) * FOUT;
        #pragma unroll
        for (int ft = 0; ft < 4; ++ft)
            #pragma unroll
            for (int r = 0; r < 4; ++r)
                nrow[(q * 4 + r) * FOUT + ft * 16 + m] = acc[ft][r];
    }
}

// ---------------------------------------------------------------------------
// k3: out[i][f] = 0.25 * sum_hd (sum_jc num[hd][jc][i][f]) / (sum_jc Zp[hd][jc][i])
// 256 blocks x 256 threads, float4 per thread; 33 MB read / 1 MB write.
// ---------------------------------------------------------------------------
__global__ __launch_bounds__(256) void gat_k3(const float* __restrict__ num,
                                              const float* __restrict__ Zp,
                                              float* __restrict__ out) {
    const int g4 = blockIdx.x * 256 + threadIdx.x;   // 0..65535
    const int i  = g4 >> 4;
    const int fo = (g4 & 15) * 4;
    float4 r = make_float4(0.f, 0.f, 0.f, 0.f);
    #pragma unroll
    for (int hd = 0; hd < 4; ++hd) {
        float4 s = make_float4(0.f, 0.f, 0.f, 0.f);
        float  z = 0.f;
        #pragma unroll
        for (int jc = 0; jc < 8; ++jc) {
            const int sl = hd * 8 + jc;
            const float4 v = *(const float4*)(num + ((size_t)sl * N + i) * FOUT + fo);
            s.x += v.x; s.y += v.y; s.z += v.z; s.w += v.w;
            z += Zp[(size_t)sl * N + i];
        }
        const float inv = 1.f / z;
        r.x += s.x * inv; r.y += s.y * inv; r.z += s.z * inv; r.w += s.w * inv;
    }
    r.x *= 0.25f; r.y *= 0.25f; r.z *= 0.25f; r.w *= 0.25f;
    *(float4*)(out + (size_t)i * FOUT + fo) = r;
}

extern "C" void kernel_launch(void* const* d_in, const int* in_sizes, int n_in,
                              void* d_out, int out_size, void* d_ws, size_t ws_size,
                              hipStream_t stream) {
    const float* x   = (const float*)d_in[0];
    const int*   adj = (const int*)d_in[1];
    const float* W   = (const float*)d_in[2];
    const float* a   = (const float*)d_in[3];
    float* out = (float*)d_out;

    short*    hF   = (short*)d_ws;                            // 2 MB
    float2*   e1f  = (float2*)(hF + (size_t)HEADS * FOUT * N);// 128 KB
    float2*   e2f  = e1f + (size_t)HEADS * N;                 // 128 KB
    unsigned* adjb = (unsigned*)(e2f + (size_t)HEADS * N);    // 2 MB
    float*    num  = (float*)(adjb + (size_t)N * 128);        // 32 MB
    float*    Zp   = num + (size_t)32 * N * FOUT;             // 512 KB

    gat_k1a<<<256, 512, 0, stream>>>(x, W, a, hF, e1f, e2f);
    gat_k1b<<<2048, 256, 0, stream>>>(adj, adjb);
    gat_k2b<<<1024, 512, 0, stream>>>(hF, adjb, e1f, e2f, num, Zp);
    gat_k3<<<256, 256, 0, stream>>>(num, Zp, out);
}

// Round 12
// 136.603 us; speedup vs baseline: 1.1622x; 1.1622x over previous
//
#include <hip/hip_runtime.h>

#define N     4096
#define FIN   256
#define CC    256   // HEADS * F_OUT
#define HEADS 4
#define FOUT  64
#define XPITCH 266  // FIN+10 shorts = 133 dwords (odd) -> conflict-free

typedef __attribute__((ext_vector_type(8))) short bf16x8;
typedef __attribute__((ext_vector_type(4))) float f32x4;
typedef __attribute__((ext_vector_type(2))) float f32x2;

// packed f32->bf16 (RNE), one instr for two values
__device__ inline unsigned cvtpk(float lo, float hi) {
    unsigned r;
    asm("v_cvt_pk_bf16_f32 %0, %1, %2" : "=v"(r) : "v"(lo), "v"(hi));
    return r;
}
// dual-FP32 packed multiply (CDNA full-rate)
__device__ inline f32x2 pkmul(f32x2 a, f32x2 b) {
    f32x2 r;
    asm("v_pk_mul_f32 %0, %1, %2" : "=v"(r) : "v"(a), "v"(b));
    return r;
}
// two masked edge weights -> one packed bf16 dword (probe-validated: this
// form is VALU-floor ~4.5 instr/edge; k2b is VALU-issue-bound per r8 PMC).
__device__ inline unsigned wpair(f32x2 E1p, float4 dd, unsigned bits, int jj) {
    const f32x2 plo = pkmul(E1p, (f32x2){dd.x, dd.y});
    const f32x2 phi = pkmul(E1p, (f32x2){dd.z, dd.w});
    const unsigned mlo = (unsigned)(((int)(bits << (31 - jj))) >> 31);
    const unsigned mhi = (unsigned)(((int)(bits << (30 - jj))) >> 31);
    const float lo = __builtin_bit_cast(float,
        __builtin_bit_cast(unsigned, fmaxf(plo[0], plo[1])) & mlo);
    const float hi = __builtin_bit_cast(float,
        __builtin_bit_cast(unsigned, fmaxf(phi[0], phi[1])) & mhi);
    return cvtpk(lo, hi);
}

// ---------------------------------------------------------------------------
// k1a: h = x@W via MFMA (one head x 64 n-rows per block, grid 256) -> hF in
// fragment order; e1/e2 stored PRE-EXPONENTIATED as {exp(e), exp(0.2e)}.
// ---------------------------------------------------------------------------
__global__ __launch_bounds__(512) void gat_k1a(const float* __restrict__ x,
                                               const float* __restrict__ W,
                                               const float* __restrict__ a,
                                               short* __restrict__ hF,
                                               float2* __restrict__ e1f,
                                               float2* __restrict__ e2f) {
    __shared__ __align__(16) short xs[64][XPITCH];    // 34.0 KB
    __shared__ __align__(16) short wts[64][XPITCH];   // 34.0 KB
    __shared__ __align__(16) short hbuf[64][74];      //  9.5 KB
    const int t    = threadIdx.x;
    const int bid  = blockIdx.x;
    const int lane = t & 63;
    const int w    = t >> 6;          // 0..7

    const int hd = bid >> 6;
    const int n0 = (bid & 63) * 64;
    const int c0 = hd * 64;
    const int m = lane & 15;
    const int q = lane >> 4;

    {   // stage x rows n0..n0+63 as bf16 (4096 float4 over 512 threads)
        const float4* xsrc = (const float4*)(x + (size_t)n0 * FIN);
        #pragma unroll
        for (int it = 0; it < 8; ++it) {
            const int fi = it * 512 + t;
            const float4 v = xsrc[fi];
            uint2 o;
            o.x = cvtpk(v.x, v.y);
            o.y = cvtpk(v.z, v.w);
            *(uint2*)&xs[fi >> 6][(fi & 63) * 4] = o;
        }
    }
    {   // stage W^T column slice (coalesced across c)
        const int c  = t & 63;
        const int k4 = (t >> 6) * 4;  // 0..28 step 4
        #pragma unroll
        for (int it = 0; it < 8; ++it) {
            const int k = it * 32 + k4;
            const float w0 = W[(k + 0) * CC + c0 + c];
            const float w1 = W[(k + 1) * CC + c0 + c];
            const float w2 = W[(k + 2) * CC + c0 + c];
            const float w3 = W[(k + 3) * CC + c0 + c];
            uint2 o;
            o.x = cvtpk(w0, w1);
            o.y = cvtpk(w2, w3);
            *(uint2*)&wts[c][k] = o;
        }
    }
    __syncthreads();

    if (w < 4) {   // compute waves: w = row-group
        f32x4 acc[4];
        #pragma unroll
        for (int ct = 0; ct < 4; ++ct) acc[ct] = (f32x4){0.f, 0.f, 0.f, 0.f};

        #pragma unroll
        for (int ks = 0; ks < 8; ++ks) {
            const bf16x8 af = *(const bf16x8*)&xs[w * 16 + m][ks * 32 + q * 8];
            #pragma unroll
            for (int ct = 0; ct < 4; ++ct) {
                const bf16x8 bf_ = *(const bf16x8*)&wts[ct * 16 + m][ks * 32 + q * 8];
                acc[ct] = __builtin_amdgcn_mfma_f32_16x16x32_bf16(af, bf_, acc[ct], 0, 0, 0);
            }
        }

        // e1/e2 from fp32 acc (C layout: row=q*4+r, col=ct*16+m)
        const float a1v[4] = {a[m], a[16 + m], a[32 + m], a[48 + m]};
        const float a2v[4] = {a[64 + m], a[80 + m], a[96 + m], a[112 + m]};
        #pragma unroll
        for (int r = 0; r < 4; ++r) {
            float s1 = 0.f, s2 = 0.f;
            #pragma unroll
            for (int ct = 0; ct < 4; ++ct) {
                s1 = fmaf(acc[ct][r], a1v[ct], s1);
                s2 = fmaf(acc[ct][r], a2v[ct], s2);
            }
            #pragma unroll
            for (int sh = 1; sh < 16; sh <<= 1) {
                s1 += __shfl_xor(s1, sh, 64);
                s2 += __shfl_xor(s2, sh, 64);
            }
            if (m == 0) {
                const int n = n0 + w * 16 + q * 4 + r;
                e1f[(size_t)hd * N + n] = make_float2(__expf(s1), __expf(0.2f * s1));
                e2f[(size_t)hd * N + n] = make_float2(__expf(s2), __expf(0.2f * s2));
            }
        }

        // transpose h tile to hbuf[c][n-local]: packed dword stores
        #pragma unroll
        for (int ct = 0; ct < 4; ++ct) {
            const unsigned lo = cvtpk(acc[ct][0], acc[ct][1]);
            const unsigned hi = cvtpk(acc[ct][2], acc[ct][3]);
            unsigned* hp = (unsigned*)&hbuf[ct * 16 + m][w * 16 + q * 4];
            hp[0] = lo;
            hp[1] = hi;
        }
    }
    __syncthreads();

    // write hF in fragment order: frag(jc32, ft) lane lp holds
    // h[f=ft*16+(lp&15)][j = jc32*32 + (lp>>4)*8 + 0..7]
    {
        const int lp = t & 63;
        const int ft = (t >> 6) & 3;
        const int c2 = t >> 8;
        const int mm = lp & 15;
        const int qq = lp >> 4;
        const bf16x8 hv = *(const bf16x8*)&hbuf[ft * 16 + mm][c2 * 32 + qq * 8];
        const size_t jc = (size_t)(n0 >> 5) + c2;
        *(bf16x8*)(hF + ((((size_t)hd * 128 + jc) * 4 + ft) * 64 + lp) * 8) = hv;
    }
}

// ---------------------------------------------------------------------------
// k1b: adj -> bitmask. Zero LDS, grid 2048 x 256 (HBM floor for the 64 MB
// stream, ~10-11 us). Wave = half-row, 8 batched int4 loads, shfl_xor pack.
// ---------------------------------------------------------------------------
__global__ __launch_bounds__(256) void gat_k1b(const int* __restrict__ adj,
                                               unsigned* __restrict__ adjb) {
    const int t    = threadIdx.x;
    const int lane = t & 63;
    const int w    = t >> 6;
    const int row  = blockIdx.x * 2 + (w >> 1);
    const int half = w & 1;
    const int4* arow4 = (const int4*)(adj + (size_t)row * N) + half * 512;
    unsigned*   drow  = adjb + (size_t)row * 128 + half * 64;

    int4 ca[8];
    #pragma unroll
    for (int k = 0; k < 8; ++k)
        ca[k] = arow4[k * 64 + lane];          // batched: 8 KB in flight
    #pragma unroll
    for (int k = 0; k < 8; ++k) {
        const int4 v = ca[k];
        unsigned n = (v.x != 0 ? 1u : 0u) | (v.y != 0 ? 2u : 0u) |
                     (v.z != 0 ? 4u : 0u) | (v.w != 0 ? 8u : 0u);
        unsigned b  = n   | ((unsigned)__shfl_xor((int)n,   1, 64) << 4);
        unsigned hw = b   | ((unsigned)__shfl_xor((int)b,   2, 64) << 8);
        unsigned d  = hw  | ((unsigned)__shfl_xor((int)hw,  4, 64) << 16);
        if ((lane & 7) == 0) drow[k * 8 + (lane >> 3)] = d;
    }
}

// ---------------------------------------------------------------------------
// k2b: numerator + Z partials via MFMA. IDENTICAL body to R9/R11; ONE change
// vs R11: __launch_bounds__(512, 4). History of this knob:
//   R9  (no bound):   allocator >64 VGPR -> only 2 blocks/CU resident
//   R11 (512,8):      allocator squeezed to 32 VGPR -> ILP collapse,
//                     VALUBusy 60.6->27%, k2b 25.2->51.8 us (measured)
//   R12 (512,4):      cap 128, measured-natural alloc = 64 (R8 PMC) ->
//                     full ILP AND 4 blocks/CU resident (VGPR 64 allows
//                     8 waves/SIMD; LDS 30KB allows 5 blocks; grid 1024
//                     supplies 4). First run with both ILP and occupancy.
// ---------------------------------------------------------------------------
__global__ __launch_bounds__(512, 4) void gat_k2b(const short* __restrict__ hF,
                                                  const unsigned* __restrict__ adjb,
                                                  const float2* __restrict__ e1f,
                                                  const float2* __restrict__ e2f,
                                                  float* __restrict__ num,
                                                  float* __restrict__ Zp) {
    __shared__ __align__(16) short    hstage[2][4096];  // 2 x 8 KB
    __shared__ __align__(16) float    e2s[1024];        // 4 KB (512 pairs)
    __shared__ __align__(16) unsigned adjl[128 * 20];   // 10 KB, pitch 20 dw
    const int t    = threadIdx.x;
    const int lane = t & 63;
    const int g    = t >> 6;
    const int bid  = blockIdx.x;
    const int xcd  = bid & 7;
    const int idx  = bid >> 3;                  // 0..127
    const int hd   = idx & 3;
    const int jc   = (idx >> 2) & 7;            // 8 chunks of 512 j
    const int it   = xcd | ((idx >> 5) << 3);   // XCD-affine i-tile (32 vals)
    const int i0   = it * 128;
    const int j0   = jc * 512;
    const int m    = lane & 15;
    const int q    = lane >> 4;
    const int slice = hd * 8 + jc;

    // stage e2 slice (512 pairs = 256 float4)
    if (t < 256)
        ((float4*)e2s)[t] = ((const float4*)(e2f + (size_t)hd * N + j0))[t];
    // stage adj slice: 128 rows x 16 dwords (this jc), pitch 20 dw (80 B;
    // byte-read banks: m*20 mod 32 -> 2-way on rows, free)
    {
        const int row  = t >> 2;                // 0..127
        const int part = t & 3;                 // uint4 0..3
        const uint4* src = (const uint4*)(adjb + (size_t)(i0 + row) * 128 + jc * 16);
        uint4* dst = (uint4*)(adjl + row * 20);
        dst[part] = src[part];
    }
    // prologue: stage macro 0 of hF (8 KB = 512 x uint4)
    const uint4* gsrc = (const uint4*)(hF + ((size_t)hd * 128 + jc * 16) * 2048);
    ((uint4*)hstage[0])[t] = gsrc[t];
    __syncthreads();

    const int    rowi = i0 + g * 16 + m;
    const float2 E1r  = e1f[(size_t)hd * N + rowi];
    const f32x2  E1pk = (f32x2){E1r.x, E1r.y};

    bf16x8 onesb;
    #pragma unroll
    for (int e = 0; e < 8; ++e) onesb[e] = (short)0x3F80;   // bf16(1.0)

    f32x4 acc[4];
    #pragma unroll
    for (int ft = 0; ft < 4; ++ft) acc[ft] = (f32x4){0.f, 0.f, 0.f, 0.f};
    f32x4 accz = (f32x4){0.f, 0.f, 0.f, 0.f};

    const unsigned char* ab = ((const unsigned char*)adjl) + (g * 16 + m) * 80 + q;

    int cur = 0;
    for (int mac = 0; mac < 8; ++mac) {
        // issue next macro's global loads FIRST (latency hides under compute)
        const uint4 v = gsrc[(size_t)((mac + 1) & 7) * 512 + t];

        const short* hb = &hstage[cur][0];
        #pragma unroll
        for (int s = 0; s < 2; ++s) {
            const int jloc = mac * 64 + s * 32 + q * 8;
            const bf16x8 b0 = *(const bf16x8*)(hb + s * 2048 + 0 * 512 + lane * 8);
            const bf16x8 b1 = *(const bf16x8*)(hb + s * 2048 + 1 * 512 + lane * 8);
            const bf16x8 b2 = *(const bf16x8*)(hb + s * 2048 + 2 * 512 + lane * 8);
            const bf16x8 b3 = *(const bf16x8*)(hb + s * 2048 + 3 * 512 + lane * 8);
            const float4* ev = (const float4*)&e2s[2 * jloc];
            const float4 d0 = ev[0], d1 = ev[1], d2 = ev[2], d3 = ev[3];
            const unsigned bits = (unsigned)ab[(mac * 2 + s) * 4];

            uint4 au;
            au.x = wpair(E1pk, d0, bits, 0);
            au.y = wpair(E1pk, d1, bits, 2);
            au.z = wpair(E1pk, d2, bits, 4);
            au.w = wpair(E1pk, d3, bits, 6);
            const bf16x8 af = __builtin_bit_cast(bf16x8, au);

            acc[0] = __builtin_amdgcn_mfma_f32_16x16x32_bf16(af, b0, acc[0], 0, 0, 0);
            acc[1] = __builtin_amdgcn_mfma_f32_16x16x32_bf16(af, b1, acc[1], 0, 0, 0);
            acc[2] = __builtin_amdgcn_mfma_f32_16x16x32_bf16(af, b2, acc[2], 0, 0, 0);
            acc[3] = __builtin_amdgcn_mfma_f32_16x16x32_bf16(af, b3, acc[3], 0, 0, 0);
            accz   = __builtin_amdgcn_mfma_f32_16x16x32_bf16(af, onesb, accz, 0, 0, 0);
        }

        if (mac < 7) {
            ((uint4*)hstage[cur ^ 1])[t] = v;   // write-late (stalls only on vmcnt)
            __syncthreads();
            cur ^= 1;
        }
    }

    // Z partials: accz reg r = masked-quantized weight row-sum (cols equal)
    if (m == 0) {
        #pragma unroll
        for (int r = 0; r < 4; ++r)
            Zp[(size_t)slice * N + i0 + g * 16 + q * 4 + r] = accz[r];
    }

    // numerator partial: C layout row=q*4+r, col=ft*16+m; plain stores
    {
        float* nrow = num + ((size_t)slice * N + i0 + g * 16) * FOUT;
        #pragma unroll
        for (int ft = 0; ft < 4; ++ft)
            #pragma unroll
            for (int r = 0; r < 4; ++r)
                nrow[(q * 4 + r) * FOUT + ft * 16 + m] = acc[ft][r];
    }
}

// ---------------------------------------------------------------------------
// k3: out[i][f] = 0.25 * sum_hd (sum_jc num[hd][jc][i][f]) / (sum_jc Zp[hd][jc][i])
// 256 blocks x 256 threads, float4 per thread; 33 MB read / 1 MB write.
// ---------------------------------------------------------------------------
__global__ __launch_bounds__(256) void gat_k3(const float* __restrict__ num,
                                              const float* __restrict__ Zp,
                                              float* __restrict__ out) {
    const int g4 = blockIdx.x * 256 + threadIdx.x;   // 0..65535
    const int i  = g4 >> 4;
    const int fo = (g4 & 15) * 4;
    float4 r = make_float4(0.f, 0.f, 0.f, 0.f);
    #pragma unroll
    for (int hd = 0; hd < 4; ++hd) {
        float4 s = make_float4(0.f, 0.f, 0.f, 0.f);
        float  z = 0.f;
        #pragma unroll
        for (int jc = 0; jc < 8; ++jc) {
            const int sl = hd * 8 + jc;
            const float4 v = *(const float4*)(num + ((size_t)sl * N + i) * FOUT + fo);
            s.x += v.x; s.y += v.y; s.z += v.z; s.w += v.w;
            z += Zp[(size_t)sl * N + i];
        }
        const float inv = 1.f / z;
        r.x += s.x * inv; r.y += s.y * inv; r.z += s.z * inv; r.w += s.w * inv;
    }
    r.x *= 0.25f; r.y *= 0.25f; r.z *= 0.25f; r.w *= 0.25f;
    *(float4*)(out + (size_t)i * FOUT + fo) = r;
}

extern "C" void kernel_launch(void* const* d_in, const int* in_sizes, int n_in,
                              void* d_out, int out_size, void* d_ws, size_t ws_size,
                              hipStream_t stream) {
    const float* x   = (const float*)d_in[0];
    const int*   adj = (const int*)d_in[1];
    const float* W   = (const float*)d_in[2];
    const float* a   = (const float*)d_in[3];
    float* out = (float*)d_out;

    short*    hF   = (short*)d_ws;                            // 2 MB
    float2*   e1f  = (float2*)(hF + (size_t)HEADS * FOUT * N);// 128 KB
    float2*   e2f  = e1f + (size_t)HEADS * N;                 // 128 KB
    unsigned* adjb = (unsigned*)(e2f + (size_t)HEADS * N);    // 2 MB
    float*    num  = (float*)(adjb + (size_t)N * 128);        // 32 MB
    float*    Zp   = num + (size_t)32 * N * FOUT;             // 512 KB

    gat_k1a<<<256, 512, 0, stream>>>(x, W, a, hF, e1f, e2f);
    gat_k1b<<<2048, 256, 0, stream>>>(adj, adjb);
    gat_k2b<<<1024, 512, 0, stream>>>(hF, adjb, e1f, e2f, num, Zp);
    gat_k3<<<256, 256, 0, stream>>>(num, Zp, out);
}

// Round 13
// 135.234 us; speedup vs baseline: 1.1739x; 1.0101x over previous
//
#include <hip/hip_runtime.h>

#define N     4096
#define FIN   256
#define CC    256   // HEADS * F_OUT
#define HEADS 4
#define FOUT  64
#define XPITCH 266  // FIN+10 shorts = 133 dwords (odd) -> conflict-free

typedef __attribute__((ext_vector_type(8))) short bf16x8;
typedef __attribute__((ext_vector_type(4))) float f32x4;
typedef __attribute__((ext_vector_type(2))) float f32x2;

// packed f32->bf16 (RNE), one instr for two values
__device__ inline unsigned cvtpk(float lo, float hi) {
    unsigned r;
    asm("v_cvt_pk_bf16_f32 %0, %1, %2" : "=v"(r) : "v"(lo), "v"(hi));
    return r;
}
// dual-FP32 packed multiply (CDNA full-rate)
__device__ inline f32x2 pkmul(f32x2 a, f32x2 b) {
    f32x2 r;
    asm("v_pk_mul_f32 %0, %1, %2" : "=v"(r) : "v"(a), "v"(b));
    return r;
}
// two masked edge weights -> one packed bf16 dword (R8 probe-validated:
// 25.2us/rep at VGPR 64 in the R5 geometry; ~4.5 VALU/edge floor).
__device__ inline unsigned wpair(f32x2 E1p, float4 dd, unsigned bits, int jj) {
    const f32x2 plo = pkmul(E1p, (f32x2){dd.x, dd.y});
    const f32x2 phi = pkmul(E1p, (f32x2){dd.z, dd.w});
    const unsigned mlo = (unsigned)(((int)(bits << (31 - jj))) >> 31);
    const unsigned mhi = (unsigned)(((int)(bits << (30 - jj))) >> 31);
    const float lo = __builtin_bit_cast(float,
        __builtin_bit_cast(unsigned, fmaxf(plo[0], plo[1])) & mlo);
    const float hi = __builtin_bit_cast(float,
        __builtin_bit_cast(unsigned, fmaxf(phi[0], phi[1])) & mhi);
    return cvtpk(lo, hi);
}

// ---------------------------------------------------------------------------
// k1a: h = x@W via MFMA (one head x 64 n-rows per block, grid 256) -> hF in
// fragment order; e1/e2 stored PRE-EXPONENTIATED as {exp(e), exp(0.2e)}.
// ---------------------------------------------------------------------------
__global__ __launch_bounds__(512) void gat_k1a(const float* __restrict__ x,
                                               const float* __restrict__ W,
                                               const float* __restrict__ a,
                                               short* __restrict__ hF,
                                               float2* __restrict__ e1f,
                                               float2* __restrict__ e2f) {
    __shared__ __align__(16) short xs[64][XPITCH];    // 34.0 KB
    __shared__ __align__(16) short wts[64][XPITCH];   // 34.0 KB
    __shared__ __align__(16) short hbuf[64][74];      //  9.5 KB
    const int t    = threadIdx.x;
    const int bid  = blockIdx.x;
    const int lane = t & 63;
    const int w    = t >> 6;          // 0..7

    const int hd = bid >> 6;
    const int n0 = (bid & 63) * 64;
    const int c0 = hd * 64;
    const int m = lane & 15;
    const int q = lane >> 4;

    {   // stage x rows n0..n0+63 as bf16 (4096 float4 over 512 threads)
        const float4* xsrc = (const float4*)(x + (size_t)n0 * FIN);
        #pragma unroll
        for (int it = 0; it < 8; ++it) {
            const int fi = it * 512 + t;
            const float4 v = xsrc[fi];
            uint2 o;
            o.x = cvtpk(v.x, v.y);
            o.y = cvtpk(v.z, v.w);
            *(uint2*)&xs[fi >> 6][(fi & 63) * 4] = o;
        }
    }
    {   // stage W^T column slice (coalesced across c)
        const int c  = t & 63;
        const int k4 = (t >> 6) * 4;  // 0..28 step 4
        #pragma unroll
        for (int it = 0; it < 8; ++it) {
            const int k = it * 32 + k4;
            const float w0 = W[(k + 0) * CC + c0 + c];
            const float w1 = W[(k + 1) * CC + c0 + c];
            const float w2 = W[(k + 2) * CC + c0 + c];
            const float w3 = W[(k + 3) * CC + c0 + c];
            uint2 o;
            o.x = cvtpk(w0, w1);
            o.y = cvtpk(w2, w3);
            *(uint2*)&wts[c][k] = o;
        }
    }
    __syncthreads();

    if (w < 4) {   // compute waves: w = row-group
        f32x4 acc[4];
        #pragma unroll
        for (int ct = 0; ct < 4; ++ct) acc[ct] = (f32x4){0.f, 0.f, 0.f, 0.f};

        #pragma unroll
        for (int ks = 0; ks < 8; ++ks) {
            const bf16x8 af = *(const bf16x8*)&xs[w * 16 + m][ks * 32 + q * 8];
            #pragma unroll
            for (int ct = 0; ct < 4; ++ct) {
                const bf16x8 bf_ = *(const bf16x8*)&wts[ct * 16 + m][ks * 32 + q * 8];
                acc[ct] = __builtin_amdgcn_mfma_f32_16x16x32_bf16(af, bf_, acc[ct], 0, 0, 0);
            }
        }

        // e1/e2 from fp32 acc (C layout: row=q*4+r, col=ct*16+m)
        const float a1v[4] = {a[m], a[16 + m], a[32 + m], a[48 + m]};
        const float a2v[4] = {a[64 + m], a[80 + m], a[96 + m], a[112 + m]};
        #pragma unroll
        for (int r = 0; r < 4; ++r) {
            float s1 = 0.f, s2 = 0.f;
            #pragma unroll
            for (int ct = 0; ct < 4; ++ct) {
                s1 = fmaf(acc[ct][r], a1v[ct], s1);
                s2 = fmaf(acc[ct][r], a2v[ct], s2);
            }
            #pragma unroll
            for (int sh = 1; sh < 16; sh <<= 1) {
                s1 += __shfl_xor(s1, sh, 64);
                s2 += __shfl_xor(s2, sh, 64);
            }
            if (m == 0) {
                const int n = n0 + w * 16 + q * 4 + r;
                e1f[(size_t)hd * N + n] = make_float2(__expf(s1), __expf(0.2f * s1));
                e2f[(size_t)hd * N + n] = make_float2(__expf(s2), __expf(0.2f * s2));
            }
        }

        // transpose h tile to hbuf[c][n-local]: packed dword stores
        #pragma unroll
        for (int ct = 0; ct < 4; ++ct) {
            const unsigned lo = cvtpk(acc[ct][0], acc[ct][1]);
            const unsigned hi = cvtpk(acc[ct][2], acc[ct][3]);
            unsigned* hp = (unsigned*)&hbuf[ct * 16 + m][w * 16 + q * 4];
            hp[0] = lo;
            hp[1] = hi;
        }
    }
    __syncthreads();

    // write hF in fragment order: frag(jc32, ft) lane lp holds
    // h[f=ft*16+(lp&15)][j = jc32*32 + (lp>>4)*8 + 0..7]
    {
        const int lp = t & 63;
        const int ft = (t >> 6) & 3;
        const int c2 = t >> 8;
        const int mm = lp & 15;
        const int qq = lp >> 4;
        const bf16x8 hv = *(const bf16x8*)&hbuf[ft * 16 + mm][c2 * 32 + qq * 8];
        const size_t jc = (size_t)(n0 >> 5) + c2;
        *(bf16x8*)(hF + ((((size_t)hd * 128 + jc) * 4 + ft) * 64 + lp) * 8) = hv;
    }
}

// ---------------------------------------------------------------------------
// k1b: adj -> bitmask. Zero LDS, grid 2048 x 256 (HBM floor for the 64 MB
// stream, ~10-11 us). Wave = half-row, 8 batched int4 loads, shfl_xor pack.
// ---------------------------------------------------------------------------
__global__ __launch_bounds__(256) void gat_k1b(const int* __restrict__ adj,
                                               unsigned* __restrict__ adjb) {
    const int t    = threadIdx.x;
    const int lane = t & 63;
    const int w    = t >> 6;
    const int row  = blockIdx.x * 2 + (w >> 1);
    const int half = w & 1;
    const int4* arow4 = (const int4*)(adj + (size_t)row * N) + half * 512;
    unsigned*   drow  = adjb + (size_t)row * 128 + half * 64;

    int4 ca[8];
    #pragma unroll
    for (int k = 0; k < 8; ++k)
        ca[k] = arow4[k * 64 + lane];          // batched: 8 KB in flight
    #pragma unroll
    for (int k = 0; k < 8; ++k) {
        const int4 v = ca[k];
        unsigned n = (v.x != 0 ? 1u : 0u) | (v.y != 0 ? 2u : 0u) |
                     (v.z != 0 ? 4u : 0u) | (v.w != 0 ? 8u : 0u);
        unsigned b  = n   | ((unsigned)__shfl_xor((int)n,   1, 64) << 4);
        unsigned hw = b   | ((unsigned)__shfl_xor((int)b,   2, 64) << 8);
        unsigned d  = hw  | ((unsigned)__shfl_xor((int)hw,  4, 64) << 16);
        if ((lane & 7) == 0) drow[k * 8 + (lane >> 3)] = d;
    }
}

// ---------------------------------------------------------------------------
// k2b: CONSOLIDATION — best-measured geometry (R5: grid 512, 128-i x
// 1024-j chunks, 16 slices => minimal k3 traffic + minimal staging
// duplication) with the R8 probe-validated body (wpair, no mtab gather)
// under (512,4) (measured VGPR=64, full ILP). Occupancy levers are closed:
// R8/R9/R11/R12 showed k2b insensitive to 16 vs 32 waves/CU and 2x worse
// when VGPR-squeezed — per-SIMD instruction issue is the saturated
// resource, so geometry with the least total overhead wins.
// ---------------------------------------------------------------------------
__global__ __launch_bounds__(512, 4) void gat_k2b(const short* __restrict__ hF,
                                                  const unsigned* __restrict__ adjb,
                                                  const float2* __restrict__ e1f,
                                                  const float2* __restrict__ e2f,
                                                  float* __restrict__ num,
                                                  float* __restrict__ Zp) {
    __shared__ __align__(16) short    hstage[2][4096];  // 2 x 8 KB
    __shared__ __align__(16) float    e2s[2048];        // 8 KB (1024 pairs)
    __shared__ __align__(16) unsigned adjl[128 * 36];   // 18 KB, pitch 36 dw
    const int t    = threadIdx.x;
    const int lane = t & 63;
    const int g    = t >> 6;
    const int bid  = blockIdx.x;
    const int xcd  = bid & 7;
    const int idx  = bid >> 3;
    const int hd   = idx & 3;
    const int jc   = (idx >> 2) & 3;            // 4 chunks of 1024 j
    const int it   = xcd | ((idx >> 4) << 3);   // XCD-affine i-tile (32 vals)
    const int i0   = it * 128;
    const int j0   = jc * 1024;
    const int m    = lane & 15;
    const int q    = lane >> 4;
    const int slice = hd * 4 + jc;

    // stage e2 slice (1024 pairs = 512 float4)
    ((float4*)e2s)[t] = ((const float4*)(e2f + (size_t)hd * N + j0))[t];
    // stage adj slice: 128 rows x 32 dwords (this jc), pitch 36 dw
    {
        const int row = t >> 2, part = t & 3;
        const uint4* src = (const uint4*)(adjb + (size_t)(i0 + row) * 128 + jc * 32 + part * 8);
        uint4* dst = (uint4*)(adjl + row * 36 + part * 8);
        dst[0] = src[0];
        dst[1] = src[1];
    }
    // prologue: stage macro 0 of hF (8 KB = 512 x uint4)
    const uint4* gsrc = (const uint4*)(hF + ((size_t)hd * 128 + jc * 32) * 2048);
    ((uint4*)hstage[0])[t] = gsrc[t];
    __syncthreads();

    const int    rowi = i0 + g * 16 + m;
    const float2 E1r  = e1f[(size_t)hd * N + rowi];
    const f32x2  E1pk = (f32x2){E1r.x, E1r.y};

    bf16x8 onesb;
    #pragma unroll
    for (int e = 0; e < 8; ++e) onesb[e] = (short)0x3F80;   // bf16(1.0)

    f32x4 acc[4];
    #pragma unroll
    for (int ft = 0; ft < 4; ++ft) acc[ft] = (f32x4){0.f, 0.f, 0.f, 0.f};
    f32x4 accz = (f32x4){0.f, 0.f, 0.f, 0.f};

    const unsigned char* ab = ((const unsigned char*)adjl) + (g * 16 + m) * 144 + q;

    int cur = 0;
    for (int mac = 0; mac < 16; ++mac) {
        // issue next macro's global loads FIRST (latency hides under compute)
        const uint4 v = gsrc[(size_t)((mac + 1) & 15) * 512 + t];

        const short* hb = &hstage[cur][0];
        #pragma unroll
        for (int s = 0; s < 2; ++s) {
            const int jloc = mac * 64 + s * 32 + q * 8;
            const bf16x8 b0 = *(const bf16x8*)(hb + s * 2048 + 0 * 512 + lane * 8);
            const bf16x8 b1 = *(const bf16x8*)(hb + s * 2048 + 1 * 512 + lane * 8);
            const bf16x8 b2 = *(const bf16x8*)(hb + s * 2048 + 2 * 512 + lane * 8);
            const bf16x8 b3 = *(const bf16x8*)(hb + s * 2048 + 3 * 512 + lane * 8);
            const float4* ev = (const float4*)&e2s[2 * jloc];
            const float4 d0 = ev[0], d1 = ev[1], d2 = ev[2], d3 = ev[3];
            const unsigned bits = (unsigned)ab[(mac * 2 + s) * 4];

            uint4 au;
            au.x = wpair(E1pk, d0, bits, 0);
            au.y = wpair(E1pk, d1, bits, 2);
            au.z = wpair(E1pk, d2, bits, 4);
            au.w = wpair(E1pk, d3, bits, 6);
            const bf16x8 af = __builtin_bit_cast(bf16x8, au);

            acc[0] = __builtin_amdgcn_mfma_f32_16x16x32_bf16(af, b0, acc[0], 0, 0, 0);
            acc[1] = __builtin_amdgcn_mfma_f32_16x16x32_bf16(af, b1, acc[1], 0, 0, 0);
            acc[2] = __builtin_amdgcn_mfma_f32_16x16x32_bf16(af, b2, acc[2], 0, 0, 0);
            acc[3] = __builtin_amdgcn_mfma_f32_16x16x32_bf16(af, b3, acc[3], 0, 0, 0);
            accz   = __builtin_amdgcn_mfma_f32_16x16x32_bf16(af, onesb, accz, 0, 0, 0);
        }

        if (mac < 15) {
            ((uint4*)hstage[cur ^ 1])[t] = v;   // write-late (stalls only on vmcnt)
            __syncthreads();
            cur ^= 1;
        }
    }

    // Z partials: accz reg r = masked-quantized weight row-sum (cols equal)
    if (m == 0) {
        #pragma unroll
        for (int r = 0; r < 4; ++r)
            Zp[(size_t)slice * N + i0 + g * 16 + q * 4 + r] = accz[r];
    }

    // numerator partial: C layout row=q*4+r, col=ft*16+m; plain stores
    {
        float* nrow = num + ((size_t)slice * N + i0 + g * 16) * FOUT;
        #pragma unroll
        for (int ft = 0; ft < 4; ++ft)
            #pragma unroll
            for (int r = 0; r < 4; ++r)
                nrow[(q * 4 + r) * FOUT + ft * 16 + m] = acc[ft][r];
    }
}

// ---------------------------------------------------------------------------
// k3: out[i][f] = 0.25 * sum_hd (sum_jc num[hd][jc][i][f]) / (sum_jc Zp[hd][jc][i])
// 256 blocks x 256 threads, float4 per thread; 17 MB read / 1 MB write.
// ---------------------------------------------------------------------------
__global__ __launch_bounds__(256) void gat_k3(const float* __restrict__ num,
                                              const float* __restrict__ Zp,
                                              float* __restrict__ out) {
    const int g4 = blockIdx.x * 256 + threadIdx.x;   // 0..65535
    const int i  = g4 >> 4;
    const int fo = (g4 & 15) * 4;
    float4 r = make_float4(0.f, 0.f, 0.f, 0.f);
    #pragma unroll
    for (int hd = 0; hd < 4; ++hd) {
        float4 s = make_float4(0.f, 0.f, 0.f, 0.f);
        float  z = 0.f;
        #pragma unroll
        for (int jc = 0; jc < 4; ++jc) {
            const int sl = hd * 4 + jc;
            const float4 v = *(const float4*)(num + ((size_t)sl * N + i) * FOUT + fo);
            s.x += v.x; s.y += v.y; s.z += v.z; s.w += v.w;
            z += Zp[(size_t)sl * N + i];
        }
        const float inv = 1.f / z;
        r.x += s.x * inv; r.y += s.y * inv; r.z += s.z * inv; r.w += s.w * inv;
    }
    r.x *= 0.25f; r.y *= 0.25f; r.z *= 0.25f; r.w *= 0.25f;
    *(float4*)(out + (size_t)i * FOUT + fo) = r;
}

extern "C" void kernel_launch(void* const* d_in, const int* in_sizes, int n_in,
                              void* d_out, int out_size, void* d_ws, size_t ws_size,
                              hipStream_t stream) {
    const float* x   = (const float*)d_in[0];
    const int*   adj = (const int*)d_in[1];
    const float* W   = (const float*)d_in[2];
    const float* a   = (const float*)d_in[3];
    float* out = (float*)d_out;

    short*    hF   = (short*)d_ws;                            // 2 MB
    float2*   e1f  = (float2*)(hF + (size_t)HEADS * FOUT * N);// 128 KB
    float2*   e2f  = e1f + (size_t)HEADS * N;                 // 128 KB
    unsigned* adjb = (unsigned*)(e2f + (size_t)HEADS * N);    // 2 MB
    float*    num  = (float*)(adjb + (size_t)N * 128);        // 16 MB
    float*    Zp   = num + (size_t)16 * N * FOUT;             // 256 KB

    gat_k1a<<<256, 512, 0, stream>>>(x, W, a, hF, e1f, e2f);
    gat_k1b<<<2048, 256, 0, stream>>>(adj, adjb);
    gat_k2b<<<512, 512, 0, stream>>>(hF, adjb, e1f, e2f, num, Zp);
    gat_k3<<<256, 256, 0, stream>>>(num, Zp, out);
}